// Round 1
// baseline (1604.584 us; speedup 1.0000x reference)
//
#include <hip/hip_runtime.h>
#include <cstddef>

#define G_    128
#define NPG_  256
#define EPG_  4096
#define NN_   32768
#define EE_   524288
#define KK_   2048
#define GK_   262144

// d_out layout (floats): [score E][causal_w GK][conf_w GK][causal_ei 2*GK][conf_ei 2*GK][cmask N][dmask N]
#define O_CW  524288
#define O_DW  786432
#define O_CEI 1048576
#define O_FEI 1572864
#define O_CM  2097152
#define O_DM  2129920

struct GemmCfg {
  const float* w[8];
  const float* b[8];
  int wstride;
};

// ---------------- GEMM: out[rows x (ncb*64)] = in[rows x 64] @ W^T (+bias) ----------------
// blockIdx.x: 64-row block; blockIdx.y: 64-col block (weights per cfg slot)
__global__ __launch_bounds__(256) void gemm_k64(const float* __restrict__ in, int istride, int relu_in,
                                                GemmCfg cfg, float* __restrict__ out, int ostride) {
  __shared__ float xT[64 * 68];
  __shared__ float wT[64 * 68];
  const int tid = threadIdx.x;
  const int r0 = blockIdx.x * 64;
  const int cb = blockIdx.y;
  const float* wp = cfg.w[cb];
  const float* bp = cfg.b[cb];
  const int wstride = cfg.wstride;
#pragma unroll
  for (int it = 0; it < 16; ++it) {
    int idx = tid + it * 256;          // 0..4095
    int rr = idx >> 6, kk = idx & 63;  // rr: row (x) / col (W); kk: k
    float v = in[(r0 + rr) * istride + kk];
    if (relu_in) v = fmaxf(v, 0.0f);
    xT[kk * 68 + rr] = v;
    wT[kk * 68 + rr] = wp[rr * wstride + kk];
  }
  __syncthreads();
  const int c4 = (tid >> 4) * 4;
  const int r4 = (tid & 15) * 4;
  float acc[4][4] = {};
#pragma unroll
  for (int k = 0; k < 64; ++k) {
    float4 xv = *(const float4*)&xT[k * 68 + r4];
    float4 wv = *(const float4*)&wT[k * 68 + c4];
    float xr[4] = {xv.x, xv.y, xv.z, xv.w};
    float wc[4] = {wv.x, wv.y, wv.z, wv.w};
#pragma unroll
    for (int a = 0; a < 4; ++a)
#pragma unroll
      for (int b = 0; b < 4; ++b)
        acc[a][b] = fmaf(xr[a], wc[b], acc[a][b]);
  }
  float bx[4] = {0.f, 0.f, 0.f, 0.f};
  if (bp) {
    float4 bb = *(const float4*)&bp[c4];
    bx[0] = bb.x; bx[1] = bb.y; bx[2] = bb.z; bx[3] = bb.w;
  }
#pragma unroll
  for (int ri = 0; ri < 4; ++ri) {
    float4 st;
    st.x = acc[ri][0] + bx[0];
    st.y = acc[ri][1] + bx[1];
    st.z = acc[ri][2] + bx[2];
    st.w = acc[ri][3] + bx[3];
    *(float4*)&out[(r0 + r4 + ri) * ostride + cb * 64 + c4] = st;
  }
}

// ---------------- per-group message scatter: h[c] (+=) sum_e w_e*(A[r_e]-B[c_e]), then h = C + agg ----------------
// buf: N x 192 rows [A(64) B(64) C(64)]; one WG per group; LDS accumulator 256x64
__global__ __launch_bounds__(256) void scatter_msgs(const float* __restrict__ buf, const int* __restrict__ ei,
                                                    const float* __restrict__ ea, float* __restrict__ hout,
                                                    int do_relu) {
  __shared__ float agg[NPG_ * 64];  // 64 KB
  const int tid = threadIdx.x;
  const int g = blockIdx.x;
  const int gbase = g * NPG_;
  for (int i = tid; i < NPG_ * 64; i += 256) agg[i] = 0.0f;
  __syncthreads();
  const int lane = tid & 63;
  const int wave = tid >> 6;
  const int e0 = g * EPG_ + wave * 1024;
  for (int chunk = 0; chunk < 1024; chunk += 64) {
    const int e = e0 + chunk + lane;
    const int r_ = ei[e];
    const int c_ = ei[EE_ + e];
    const float w_ = ea[e];
#pragma unroll 4
    for (int j = 0; j < 64; ++j) {
      int rj = __shfl(r_, j);
      int cj = __shfl(c_, j);
      float wj = __shfl(w_, j);
      float a = buf[rj * 192 + lane];
      float b = buf[cj * 192 + 64 + lane];
      atomicAdd(&agg[(cj - gbase) * 64 + lane], wj * (a - b));
    }
  }
  __syncthreads();
  for (int i = tid; i < NPG_ * 64; i += 256) {
    int node = i >> 6, k = i & 63;
    float v = buf[(gbase + node) * 192 + 128 + k] + agg[i];
    if (do_relu) v = fmaxf(v, 0.0f);
    hout[(gbase + node) * 64 + k] = v;
  }
}

// ---------------- edge scores: score_e = Wm2 . relu(P[r]+Q[c]) + bm2, wave per edge ----------------
__global__ __launch_bounds__(256) void score_kernel(const float* __restrict__ pq, const int* __restrict__ ei,
                                                    const float* __restrict__ wm2, const float* __restrict__ bm2,
                                                    float* __restrict__ out) {
  const int tid = threadIdx.x;
  const int lane = tid & 63;
  const int wave = tid >> 6;
  const int e0 = (blockIdx.x * 4 + wave) * 64;
  const float4 w2 = *(const float4*)&wm2[lane * 4];
  const float beta = bm2[0];
  const int r_ = ei[e0 + lane];
  const int c_ = ei[EE_ + e0 + lane];
  float my = 0.0f;
  for (int j = 0; j < 64; ++j) {
    int rj = __shfl(r_, j);
    int cj = __shfl(c_, j);
    float4 p = *(const float4*)&pq[rj * 512 + lane * 4];
    float4 q = *(const float4*)&pq[cj * 512 + 256 + lane * 4];
    float s = fmaxf(p.x + q.x, 0.f) * w2.x;
    s = fmaf(fmaxf(p.y + q.y, 0.f), w2.y, s);
    s = fmaf(fmaxf(p.z + q.z, 0.f), w2.z, s);
    s = fmaf(fmaxf(p.w + q.w, 0.f), w2.w, s);
#pragma unroll
    for (int off = 32; off > 0; off >>= 1) s += __shfl_xor(s, off);
    if (lane == j) my = s + beta;
  }
  out[e0 + lane] = my;
}

// ---------------- per-group stable-descending bitonic argsort + top-K split ----------------
// key = (orderable(score) << 32) | ~idx  -> descending sort == argsort(-s) stable
__global__ __launch_bounds__(1024) void sort_kernel(float* __restrict__ out, const int* __restrict__ ei,
                                                    int* __restrict__ kg, int* __restrict__ dg,
                                                    int* __restrict__ cmask, int* __restrict__ dmask) {
  __shared__ unsigned long long keys[EPG_];  // 32 KB
  const int g = blockIdx.x;
  const int tid = threadIdx.x;
  for (int i = tid; i < EPG_; i += 1024) {
    float s = out[g * EPG_ + i];
    unsigned u = __float_as_uint(s);
    u = (u & 0x80000000u) ? ~u : (u | 0x80000000u);
    keys[i] = ((unsigned long long)u << 32) | (unsigned)(~i);
  }
  __syncthreads();
  for (int k = 2; k <= EPG_; k <<= 1) {
    for (int j = k >> 1; j > 0; j >>= 1) {
      for (int i = tid; i < EPG_; i += 1024) {
        int ixj = i ^ j;
        if (ixj > i) {
          unsigned long long a = keys[i], b = keys[ixj];
          bool desc = ((i & k) == 0);
          if ((a < b) == desc) { keys[i] = b; keys[ixj] = a; }
        }
      }
      __syncthreads();
    }
  }
  for (int p = tid; p < EPG_; p += 1024) {
    unsigned long long kv = keys[p];
    int i = (int)(~(unsigned)kv);
    unsigned hi = (unsigned)(kv >> 32);
    unsigned ub = (hi & 0x80000000u) ? (hi ^ 0x80000000u) : ~hi;
    float s = __uint_as_float(ub);
    int e = g * EPG_ + i;
    int r = ei[e], c = ei[EE_ + e];
    if (p < KK_) {
      out[O_CW + g * KK_ + p] = s;
      kg[g * KK_ + p] = e;
      cmask[r] = 1; cmask[c] = 1;
    } else {
      int q = p - KK_;
      out[O_DW + g * KK_ + q] = -s;
      dg[g * KK_ + q] = e;
      dmask[r] = 1; dmask[c] = 1;
    }
  }
}

// ---------------- inclusive scan of masks -> nid (cumsum-1); 1 block per mask ----------------
__global__ __launch_bounds__(1024) void scan_kernel(const int* __restrict__ masks, int* __restrict__ nids) {
  const int which = blockIdx.x;
  const int* m = masks + which * NN_;
  int* nid = nids + which * NN_;
  const int tid = threadIdx.x;
  const int base = tid * 32;
  int local[32];
  int sum = 0;
#pragma unroll
  for (int j = 0; j < 32; ++j) { local[j] = m[base + j]; sum += local[j]; }
  __shared__ int ps[1024];
  ps[tid] = sum;
  __syncthreads();
  for (int off = 1; off < 1024; off <<= 1) {
    int v = (tid >= off) ? ps[tid - off] : 0;
    __syncthreads();
    ps[tid] += v;
    __syncthreads();
  }
  int run = ps[tid] - sum;  // exclusive prefix over this thread's chunk
#pragma unroll
  for (int j = 0; j < 32; ++j) { run += local[j]; nid[base + j] = run - 1; }
}

// ---------------- final gathers: relabeled edge indices + masks as floats ----------------
__global__ __launch_bounds__(256) void finalize_kernel(const int* __restrict__ kg, const int* __restrict__ dg,
                                                       const int* __restrict__ ei,
                                                       const int* __restrict__ nid_c, const int* __restrict__ nid_d,
                                                       const int* __restrict__ cmask, const int* __restrict__ dmask,
                                                       float* __restrict__ out) {
  const int p = blockIdx.x * 256 + threadIdx.x;  // p < GK_
  int e = kg[p];
  out[O_CEI + p]       = (float)nid_c[ei[e]];
  out[O_CEI + GK_ + p] = (float)nid_c[ei[EE_ + e]];
  int e2 = dg[p];
  out[O_FEI + p]       = (float)nid_d[ei[e2]];
  out[O_FEI + GK_ + p] = (float)nid_d[ei[EE_ + e2]];
  if (p < NN_) {
    out[O_CM + p] = (float)cmask[p];
    out[O_DM + p] = (float)dmask[p];
  }
}

extern "C" void kernel_launch(void* const* d_in, const int* in_sizes, int n_in,
                              void* d_out, int out_size, void* d_ws, size_t ws_size,
                              hipStream_t stream) {
  (void)in_sizes; (void)n_in; (void)out_size; (void)ws_size;
  const float* x   = (const float*)d_in[0];
  const float* ea  = (const float*)d_in[1];
  const float* W11 = (const float*)d_in[2];
  const float* b11 = (const float*)d_in[3];
  const float* W12 = (const float*)d_in[4];
  const float* W13 = (const float*)d_in[5];
  const float* b13 = (const float*)d_in[6];
  const float* W21 = (const float*)d_in[7];
  const float* b21 = (const float*)d_in[8];
  const float* W22 = (const float*)d_in[9];
  const float* W23 = (const float*)d_in[10];
  const float* b23 = (const float*)d_in[11];
  const float* Wm1 = (const float*)d_in[12];
  const float* bm1 = (const float*)d_in[13];
  const float* Wm2 = (const float*)d_in[14];
  const float* bm2 = (const float*)d_in[15];
  const int*   ei  = (const int*)d_in[16];
  float* out = (float*)d_out;
  float* ws  = (float*)d_ws;

  // workspace (float offsets), phase-overlapped:
  //   pq   [0, 16777216)        (N x 512)  -- written after bufA/bufB are dead
  //   bufA [0, 6291456)         (N x 192)  gemm1 out
  //   bufB [6291456, 12582912)  (N x 192)  gemm2 out
  //   h_c  [16777216, 18874368) (N x 64)   h1 then h2
  //   ints from 18874368: kg GK, dg GK, cmask N, dmask N, nid_c N, nid_d N
  float* bufA = ws;
  float* bufB = ws + 6291456;
  float* pq   = ws;
  float* h_c  = ws + 16777216;
  int* kg    = (int*)(ws + 18874368);
  int* dg    = kg + GK_;
  int* cmask = dg + GK_;
  int* dmask = cmask + NN_;
  int* nid_c = dmask + NN_;
  int* nid_d = nid_c + NN_;

  hipMemsetAsync(cmask, 0, 2 * NN_ * sizeof(int), stream);

  GemmCfg c1{};
  c1.w[0] = W11; c1.w[1] = W12; c1.w[2] = W13;
  c1.b[0] = b11; c1.b[1] = nullptr; c1.b[2] = b13;
  c1.wstride = 64;
  gemm_k64<<<dim3(512, 3), 256, 0, stream>>>(x, 64, 0, c1, bufA, 192);

  scatter_msgs<<<G_, 256, 0, stream>>>(bufA, ei, ea, h_c, /*relu=*/1);

  GemmCfg c2{};
  c2.w[0] = W21; c2.w[1] = W22; c2.w[2] = W23;
  c2.b[0] = b21; c2.b[1] = nullptr; c2.b[2] = b23;
  c2.wstride = 64;
  gemm_k64<<<dim3(512, 3), 256, 0, stream>>>(h_c, 64, 0, c2, bufB, 192);

  scatter_msgs<<<G_, 256, 0, stream>>>(bufB, ei, ea, h_c, /*relu=*/0);

  GemmCfg c3{};
  for (int cb = 0; cb < 4; ++cb) { c3.w[cb] = Wm1 + cb * 64 * 128;            c3.b[cb] = bm1 + cb * 64; }
  for (int cb = 4; cb < 8; ++cb) { c3.w[cb] = Wm1 + (cb - 4) * 64 * 128 + 64; c3.b[cb] = nullptr; }
  c3.wstride = 128;
  gemm_k64<<<dim3(512, 8), 256, 0, stream>>>(h_c, 64, 0, c3, pq, 512);

  score_kernel<<<EE_ / 256, 256, 0, stream>>>(pq, ei, Wm2, bm2, out);

  sort_kernel<<<G_, 1024, 0, stream>>>(out, ei, kg, dg, cmask, dmask);

  scan_kernel<<<2, 1024, 0, stream>>>(cmask, nid_c);

  finalize_kernel<<<GK_ / 256, 256, 0, stream>>>(kg, dg, ei, nid_c, nid_d, cmask, dmask, out);
}

// Round 2
// 934.687 us; speedup vs baseline: 1.7167x; 1.7167x over previous
//
#include <hip/hip_runtime.h>
#include <cstddef>

#define G_    128
#define NPG_  256
#define EPG_  4096
#define NN_   32768
#define EE_   524288
#define KK_   2048
#define GK_   262144

// d_out layout (floats): [score E][causal_w GK][conf_w GK][causal_ei 2*GK][conf_ei 2*GK][cmask N][dmask N]
#define O_CW  524288
#define O_DW  786432
#define O_CEI 1048576
#define O_FEI 1572864
#define O_CM  2097152
#define O_DM  2129920

struct GemmCfg {
  const float* w[8];
  const float* b[8];
  int wstride;
};

// ---------------- GEMM: out[rows x (ncb*64)] = in[rows x 64] @ W^T (+bias) ----------------
__global__ __launch_bounds__(256) void gemm_k64(const float* __restrict__ in, int istride, int relu_in,
                                                GemmCfg cfg, float* __restrict__ out, int ostride) {
  __shared__ float xT[64 * 68];
  __shared__ float wT[64 * 68];
  const int tid = threadIdx.x;
  const int r0 = blockIdx.x * 64;
  const int cb = blockIdx.y;
  const float* wp = cfg.w[cb];
  const float* bp = cfg.b[cb];
  const int wstride = cfg.wstride;
#pragma unroll
  for (int it = 0; it < 16; ++it) {
    int idx = tid + it * 256;
    int rr = idx >> 6, kk = idx & 63;
    float v = in[(r0 + rr) * istride + kk];
    if (relu_in) v = fmaxf(v, 0.0f);
    xT[kk * 68 + rr] = v;
    wT[kk * 68 + rr] = wp[rr * wstride + kk];
  }
  __syncthreads();
  const int c4 = (tid >> 4) * 4;
  const int r4 = (tid & 15) * 4;
  float acc[4][4] = {};
#pragma unroll
  for (int k = 0; k < 64; ++k) {
    float4 xv = *(const float4*)&xT[k * 68 + r4];
    float4 wv = *(const float4*)&wT[k * 68 + c4];
    float xr[4] = {xv.x, xv.y, xv.z, xv.w};
    float wc[4] = {wv.x, wv.y, wv.z, wv.w};
#pragma unroll
    for (int a = 0; a < 4; ++a)
#pragma unroll
      for (int b = 0; b < 4; ++b)
        acc[a][b] = fmaf(xr[a], wc[b], acc[a][b]);
  }
  float bx[4] = {0.f, 0.f, 0.f, 0.f};
  if (bp) {
    float4 bb = *(const float4*)&bp[c4];
    bx[0] = bb.x; bx[1] = bb.y; bx[2] = bb.z; bx[3] = bb.w;
  }
#pragma unroll
  for (int ri = 0; ri < 4; ++ri) {
    float4 st;
    st.x = acc[ri][0] + bx[0];
    st.y = acc[ri][1] + bx[1];
    st.z = acc[ri][2] + bx[2];
    st.w = acc[ri][3] + bx[3];
    *(float4*)&out[(r0 + r4 + ri) * ostride + cb * 64 + c4] = st;
  }
}

// ---------------- build dense per-group weight matrix MT[g][r][c] += w_e, Wc[col] += w_e ----------------
__global__ __launch_bounds__(256) void build_M(const int* __restrict__ ei, const float* __restrict__ ea,
                                               float* __restrict__ MT, float* __restrict__ Wc) {
  const int e = blockIdx.x * 256 + threadIdx.x;
  const int r = ei[e];
  const int c = ei[EE_ + e];
  const int g = e >> 12;
  const int gb = g << 8;
  const float w = ea[e];
  atomicAdd(&MT[((size_t)g << 16) + ((size_t)(r - gb) << 8) + (c - gb)], w);
  atomicAdd(&Wc[c], w);
}

// ---------------- dense leconv aggregation: h[c] = sum_r MT[r][c]*A[r] - Wc[c]*B[c] + C[c] (+relu) ----------------
// buf rows: [A(64) | B(64) | C(64)] stride 192. One block per 64 output nodes.
__global__ __launch_bounds__(256) void mm_agg(const float* __restrict__ MT, const float* __restrict__ buf,
                                              const float* __restrict__ Wc, float* __restrict__ hout,
                                              int do_relu) {
  __shared__ float Ms[64 * 72];
  __shared__ float As[64 * 72];
  const int tid = threadIdx.x;
  const int g = blockIdx.x >> 2;
  const int c0 = (blockIdx.x & 3) * 64;
  const int gbase = g * NPG_;
  const size_t mbase = (size_t)g << 16;
  const int c4 = (tid & 15) * 4;   // output node within tile
  const int k4 = (tid >> 4) * 4;   // feature
  float acc[4][4] = {};
  for (int kc = 0; kc < 4; ++kc) {
#pragma unroll
    for (int it = 0; it < 16; ++it) {
      int idx = tid + it * 256;
      int rr = idx >> 6, cc = idx & 63;
      Ms[rr * 72 + cc] = MT[mbase + (size_t)(kc * 64 + rr) * 256 + c0 + cc];
      As[rr * 72 + cc] = buf[(gbase + kc * 64 + rr) * 192 + cc];
    }
    __syncthreads();
#pragma unroll
    for (int r = 0; r < 64; ++r) {
      float4 mv = *(const float4*)&Ms[r * 72 + c4];
      float4 av = *(const float4*)&As[r * 72 + k4];
      float mr[4] = {mv.x, mv.y, mv.z, mv.w};
      float ak[4] = {av.x, av.y, av.z, av.w};
#pragma unroll
      for (int ci = 0; ci < 4; ++ci)
#pragma unroll
        for (int ki = 0; ki < 4; ++ki)
          acc[ci][ki] = fmaf(mr[ci], ak[ki], acc[ci][ki]);
    }
    __syncthreads();
  }
#pragma unroll
  for (int ci = 0; ci < 4; ++ci) {
    int n = gbase + c0 + c4 + ci;
    float wcn = Wc[n];
    float4 b4 = *(const float4*)&buf[n * 192 + 64 + k4];
    float4 cc4 = *(const float4*)&buf[n * 192 + 128 + k4];
    float4 st;
    st.x = acc[ci][0] - wcn * b4.x + cc4.x;
    st.y = acc[ci][1] - wcn * b4.y + cc4.y;
    st.z = acc[ci][2] - wcn * b4.z + cc4.z;
    st.w = acc[ci][3] - wcn * b4.w + cc4.w;
    if (do_relu) {
      st.x = fmaxf(st.x, 0.f); st.y = fmaxf(st.y, 0.f);
      st.z = fmaxf(st.z, 0.f); st.w = fmaxf(st.w, 0.f);
    }
    *(float4*)&hout[n * 64 + k4] = st;
  }
}

// ---------------- edge scores: score_e = Wm2 . relu(P[r]+Q[c]) + bm2, wave per 64 edges ----------------
__global__ __launch_bounds__(256) void score_kernel(const float* __restrict__ pq, const int* __restrict__ ei,
                                                    const float* __restrict__ wm2, const float* __restrict__ bm2,
                                                    float* __restrict__ out) {
  const int tid = threadIdx.x;
  const int lane = tid & 63;
  const int wave = tid >> 6;
  const int e0 = (blockIdx.x * 4 + wave) * 64;
  const float4 w2 = *(const float4*)&wm2[lane * 4];
  const float beta = bm2[0];
  const int r_ = ei[e0 + lane];
  const int c_ = ei[EE_ + e0 + lane];
  float my = 0.0f;
  for (int j = 0; j < 64; ++j) {
    int rj = __shfl(r_, j);
    int cj = __shfl(c_, j);
    float4 p = *(const float4*)&pq[rj * 512 + lane * 4];
    float4 q = *(const float4*)&pq[cj * 512 + 256 + lane * 4];
    float s = fmaxf(p.x + q.x, 0.f) * w2.x;
    s = fmaf(fmaxf(p.y + q.y, 0.f), w2.y, s);
    s = fmaf(fmaxf(p.z + q.z, 0.f), w2.z, s);
    s = fmaf(fmaxf(p.w + q.w, 0.f), w2.w, s);
#pragma unroll
    for (int off = 32; off > 0; off >>= 1) s += __shfl_xor(s, off);
    if (lane == j) my = s + beta;
  }
  out[e0 + lane] = my;
}

// ---------------- per-group stable-descending bitonic argsort + top-K split ----------------
__global__ __launch_bounds__(1024) void sort_kernel(float* __restrict__ out, const int* __restrict__ ei,
                                                    int* __restrict__ kg, int* __restrict__ dg,
                                                    int* __restrict__ cmask, int* __restrict__ dmask) {
  __shared__ unsigned long long keys[EPG_];
  const int g = blockIdx.x;
  const int tid = threadIdx.x;
  for (int i = tid; i < EPG_; i += 1024) {
    float s = out[g * EPG_ + i];
    unsigned u = __float_as_uint(s);
    u = (u & 0x80000000u) ? ~u : (u | 0x80000000u);
    keys[i] = ((unsigned long long)u << 32) | (unsigned)(~i);
  }
  __syncthreads();
  for (int k = 2; k <= EPG_; k <<= 1) {
    for (int j = k >> 1; j > 0; j >>= 1) {
      for (int i = tid; i < EPG_; i += 1024) {
        int ixj = i ^ j;
        if (ixj > i) {
          unsigned long long a = keys[i], b = keys[ixj];
          bool desc = ((i & k) == 0);
          if ((a < b) == desc) { keys[i] = b; keys[ixj] = a; }
        }
      }
      __syncthreads();
    }
  }
  for (int p = tid; p < EPG_; p += 1024) {
    unsigned long long kv = keys[p];
    int i = (int)(~(unsigned)kv);
    unsigned hi = (unsigned)(kv >> 32);
    unsigned ub = (hi & 0x80000000u) ? (hi ^ 0x80000000u) : ~hi;
    float s = __uint_as_float(ub);
    int e = g * EPG_ + i;
    int r = ei[e], c = ei[EE_ + e];
    if (p < KK_) {
      out[O_CW + g * KK_ + p] = s;
      kg[g * KK_ + p] = e;
      cmask[r] = 1; cmask[c] = 1;
    } else {
      int q = p - KK_;
      out[O_DW + g * KK_ + q] = -s;
      dg[g * KK_ + q] = e;
      dmask[r] = 1; dmask[c] = 1;
    }
  }
}

// ---------------- inclusive scan of masks -> nid (cumsum-1); 1 block per mask ----------------
__global__ __launch_bounds__(1024) void scan_kernel(const int* __restrict__ masks, int* __restrict__ nids) {
  const int which = blockIdx.x;
  const int* m = masks + which * NN_;
  int* nid = nids + which * NN_;
  const int tid = threadIdx.x;
  const int base = tid * 32;
  int local[32];
  int sum = 0;
#pragma unroll
  for (int j = 0; j < 32; ++j) { local[j] = m[base + j]; sum += local[j]; }
  __shared__ int ps[1024];
  ps[tid] = sum;
  __syncthreads();
  for (int off = 1; off < 1024; off <<= 1) {
    int v = (tid >= off) ? ps[tid - off] : 0;
    __syncthreads();
    ps[tid] += v;
    __syncthreads();
  }
  int run = ps[tid] - sum;
#pragma unroll
  for (int j = 0; j < 32; ++j) { run += local[j]; nid[base + j] = run - 1; }
}

// ---------------- final gathers ----------------
__global__ __launch_bounds__(256) void finalize_kernel(const int* __restrict__ kg, const int* __restrict__ dg,
                                                       const int* __restrict__ ei,
                                                       const int* __restrict__ nid_c, const int* __restrict__ nid_d,
                                                       const int* __restrict__ cmask, const int* __restrict__ dmask,
                                                       float* __restrict__ out) {
  const int p = blockIdx.x * 256 + threadIdx.x;
  int e = kg[p];
  out[O_CEI + p]       = (float)nid_c[ei[e]];
  out[O_CEI + GK_ + p] = (float)nid_c[ei[EE_ + e]];
  int e2 = dg[p];
  out[O_FEI + p]       = (float)nid_d[ei[e2]];
  out[O_FEI + GK_ + p] = (float)nid_d[ei[EE_ + e2]];
  if (p < NN_) {
    out[O_CM + p] = (float)cmask[p];
    out[O_DM + p] = (float)dmask[p];
  }
}

extern "C" void kernel_launch(void* const* d_in, const int* in_sizes, int n_in,
                              void* d_out, int out_size, void* d_ws, size_t ws_size,
                              hipStream_t stream) {
  (void)in_sizes; (void)n_in; (void)out_size; (void)ws_size;
  const float* x   = (const float*)d_in[0];
  const float* ea  = (const float*)d_in[1];
  const float* W11 = (const float*)d_in[2];
  const float* b11 = (const float*)d_in[3];
  const float* W12 = (const float*)d_in[4];
  const float* W13 = (const float*)d_in[5];
  const float* b13 = (const float*)d_in[6];
  const float* W21 = (const float*)d_in[7];
  const float* b21 = (const float*)d_in[8];
  const float* W22 = (const float*)d_in[9];
  const float* W23 = (const float*)d_in[10];
  const float* b23 = (const float*)d_in[11];
  const float* Wm1 = (const float*)d_in[12];
  const float* bm1 = (const float*)d_in[13];
  const float* Wm2 = (const float*)d_in[14];
  const float* bm2 = (const float*)d_in[15];
  const int*   ei  = (const int*)d_in[16];
  float* out = (float*)d_out;
  float* ws  = (float*)d_ws;

  // workspace (float offsets), phase-overlapped (78.2 MB total):
  //   MT  [0, 8388608)          32 MB  dense group matrices (dead after mm_agg #2)
  //   buf [8388608, 14680064)   24 MB  N x 192 [A|B|C], reused by both layers (dead after mm_agg #2)
  //   Wc  [14680064, 14712832)  128 KB (dead after mm_agg #2)
  //   pq  [0, 16777216)         64 MB  N x 512 -- overlaps MT/buf/Wc, written after both are dead
  //   h_c [16777216, 18874368)  8 MB   h1 then h2
  //   ints from 18874368: kg GK, dg GK, cmask N, dmask N, nid_c N, nid_d N
  float* MT  = ws;
  float* buf = ws + 8388608;
  float* Wc  = ws + 14680064;
  float* pq  = ws;
  float* h_c = ws + 16777216;
  int* kg    = (int*)(ws + 18874368);
  int* dg    = kg + GK_;
  int* cmask = dg + GK_;
  int* dmask = cmask + NN_;
  int* nid_c = dmask + NN_;
  int* nid_d = nid_c + NN_;

  hipMemsetAsync(MT, 0, (size_t)G_ * NPG_ * NPG_ * sizeof(float), stream);
  hipMemsetAsync(Wc, 0, NN_ * sizeof(float), stream);
  hipMemsetAsync(cmask, 0, 2 * NN_ * sizeof(int), stream);

  build_M<<<EE_ / 256, 256, 0, stream>>>(ei, ea, MT, Wc);

  GemmCfg c1{};
  c1.w[0] = W11; c1.w[1] = W12; c1.w[2] = W13;
  c1.b[0] = b11; c1.b[1] = nullptr; c1.b[2] = b13;
  c1.wstride = 64;
  gemm_k64<<<dim3(512, 3), 256, 0, stream>>>(x, 64, 0, c1, buf, 192);

  mm_agg<<<512, 256, 0, stream>>>(MT, buf, Wc, h_c, /*relu=*/1);

  GemmCfg c2{};
  c2.w[0] = W21; c2.w[1] = W22; c2.w[2] = W23;
  c2.b[0] = b21; c2.b[1] = nullptr; c2.b[2] = b23;
  c2.wstride = 64;
  gemm_k64<<<dim3(512, 3), 256, 0, stream>>>(h_c, 64, 0, c2, buf, 192);

  mm_agg<<<512, 256, 0, stream>>>(MT, buf, Wc, h_c, /*relu=*/0);

  GemmCfg c3{};
  for (int cb = 0; cb < 4; ++cb) { c3.w[cb] = Wm1 + cb * 64 * 128;            c3.b[cb] = bm1 + cb * 64; }
  for (int cb = 4; cb < 8; ++cb) { c3.w[cb] = Wm1 + (cb - 4) * 64 * 128 + 64; c3.b[cb] = nullptr; }
  c3.wstride = 128;
  gemm_k64<<<dim3(512, 8), 256, 0, stream>>>(h_c, 64, 0, c3, pq, 512);

  score_kernel<<<EE_ / 256, 256, 0, stream>>>(pq, ei, Wm2, bm2, out);

  sort_kernel<<<G_, 1024, 0, stream>>>(out, ei, kg, dg, cmask, dmask);

  scan_kernel<<<2, 1024, 0, stream>>>(cmask, nid_c);

  finalize_kernel<<<GK_ / 256, 256, 0, stream>>>(kg, dg, ei, nid_c, nid_d, cmask, dmask, out);
}

// Round 3
// 475.848 us; speedup vs baseline: 3.3721x; 1.9643x over previous
//
#include <hip/hip_runtime.h>
#include <cstddef>

#define G_    128
#define NPG_  256
#define EPG_  4096
#define NN_   32768
#define EE_   524288
#define KK_   2048
#define GK_   262144

// d_out layout (floats): [score E][causal_w GK][conf_w GK][causal_ei 2*GK][conf_ei 2*GK][cmask N][dmask N]
#define O_CW  524288
#define O_DW  786432
#define O_CEI 1048576
#define O_FEI 1572864
#define O_CM  2097152
#define O_DM  2129920

struct GemmCfg {
  const float* w[8];
  const float* b[8];
  int wstride;
};

// ---------------- GEMM v2: x-tile resident, loop col-blocks internally ----------------
// out[rows x (ncb*64)] = in[rows x 64] @ W_cb^T (+bias_cb) for cb in [0,ncb)
__global__ __launch_bounds__(256, 4) void gemm_k64(const float* __restrict__ in, int istride,
                                                   GemmCfg cfg, int ncb,
                                                   float* __restrict__ out, int ostride) {
  __shared__ float xT[64 * 68];
  __shared__ float wT[64 * 68];
  const int tid = threadIdx.x;
  const int r0 = blockIdx.x * 64;
  const int wstride = cfg.wstride;
#pragma unroll
  for (int it = 0; it < 16; ++it) {
    int idx = tid + it * 256;
    int rr = idx >> 6, kk = idx & 63;
    xT[kk * 68 + rr] = in[(r0 + rr) * istride + kk];
  }
  const int c4 = (tid >> 4) * 4;
  const int r4 = (tid & 15) * 4;
  for (int cb = 0; cb < ncb; ++cb) {
    const float* wp = cfg.w[cb];
    const float* bp = cfg.b[cb];
    __syncthreads();  // xT ready (cb=0) / wT no longer read (cb>0)
#pragma unroll
    for (int it = 0; it < 16; ++it) {
      int idx = tid + it * 256;
      int rr = idx >> 6, kk = idx & 63;
      wT[kk * 68 + rr] = wp[rr * wstride + kk];
    }
    __syncthreads();
    float acc[4][4] = {};
#pragma unroll
    for (int k = 0; k < 64; ++k) {
      float4 xv = *(const float4*)&xT[k * 68 + r4];
      float4 wv = *(const float4*)&wT[k * 68 + c4];
      float xr[4] = {xv.x, xv.y, xv.z, xv.w};
      float wc[4] = {wv.x, wv.y, wv.z, wv.w};
#pragma unroll
      for (int a = 0; a < 4; ++a)
#pragma unroll
        for (int b = 0; b < 4; ++b)
          acc[a][b] = fmaf(xr[a], wc[b], acc[a][b]);
    }
    float bx[4] = {0.f, 0.f, 0.f, 0.f};
    if (bp) {
      float4 bb = *(const float4*)&bp[c4];
      bx[0] = bb.x; bx[1] = bb.y; bx[2] = bb.z; bx[3] = bb.w;
    }
#pragma unroll
    for (int ri = 0; ri < 4; ++ri) {
      float4 st;
      st.x = acc[ri][0] + bx[0];
      st.y = acc[ri][1] + bx[1];
      st.z = acc[ri][2] + bx[2];
      st.w = acc[ri][3] + bx[3];
      *(float4*)&out[(r0 + r4 + ri) * ostride + cb * 64 + c4] = st;
    }
  }
}

// ---------------- build dense per-group weight matrix MT[g][r][c] += w_e, Wc[col] += w_e ----------------
__global__ __launch_bounds__(256) void build_M(const int* __restrict__ ei, const float* __restrict__ ea,
                                               float* __restrict__ MT, float* __restrict__ Wc) {
  const int e = blockIdx.x * 256 + threadIdx.x;
  const int r = ei[e];
  const int c = ei[EE_ + e];
  const int g = e >> 12;
  const int gb = g << 8;
  const float w = ea[e];
  atomicAdd(&MT[((size_t)g << 16) + ((size_t)(r - gb) << 8) + (c - gb)], w);
  atomicAdd(&Wc[c], w);
}

// ---------------- dense leconv aggregation: h[c] = sum_r MT[r][c]*A[r] - Wc[c]*B[c] + C[c] (+relu) ----------------
__global__ __launch_bounds__(256) void mm_agg(const float* __restrict__ MT, const float* __restrict__ buf,
                                              const float* __restrict__ Wc, float* __restrict__ hout,
                                              int do_relu) {
  __shared__ float Ms[64 * 72];
  __shared__ float As[64 * 72];
  const int tid = threadIdx.x;
  const int g = blockIdx.x >> 2;
  const int c0 = (blockIdx.x & 3) * 64;
  const int gbase = g * NPG_;
  const size_t mbase = (size_t)g << 16;
  const int c4 = (tid & 15) * 4;
  const int k4 = (tid >> 4) * 4;
  float acc[4][4] = {};
  for (int kc = 0; kc < 4; ++kc) {
#pragma unroll
    for (int it = 0; it < 16; ++it) {
      int idx = tid + it * 256;
      int rr = idx >> 6, cc = idx & 63;
      Ms[rr * 72 + cc] = MT[mbase + (size_t)(kc * 64 + rr) * 256 + c0 + cc];
      As[rr * 72 + cc] = buf[(gbase + kc * 64 + rr) * 192 + cc];
    }
    __syncthreads();
#pragma unroll
    for (int r = 0; r < 64; ++r) {
      float4 mv = *(const float4*)&Ms[r * 72 + c4];
      float4 av = *(const float4*)&As[r * 72 + k4];
      float mr[4] = {mv.x, mv.y, mv.z, mv.w};
      float ak[4] = {av.x, av.y, av.z, av.w};
#pragma unroll
      for (int ci = 0; ci < 4; ++ci)
#pragma unroll
        for (int ki = 0; ki < 4; ++ki)
          acc[ci][ki] = fmaf(mr[ci], ak[ki], acc[ci][ki]);
    }
    __syncthreads();
  }
#pragma unroll
  for (int ci = 0; ci < 4; ++ci) {
    int n = gbase + c0 + c4 + ci;
    float wcn = Wc[n];
    float4 b4 = *(const float4*)&buf[n * 192 + 64 + k4];
    float4 cc4 = *(const float4*)&buf[n * 192 + 128 + k4];
    float4 st;
    st.x = acc[ci][0] - wcn * b4.x + cc4.x;
    st.y = acc[ci][1] - wcn * b4.y + cc4.y;
    st.z = acc[ci][2] - wcn * b4.z + cc4.z;
    st.w = acc[ci][3] - wcn * b4.w + cc4.w;
    if (do_relu) {
      st.x = fmaxf(st.x, 0.f); st.y = fmaxf(st.y, 0.f);
      st.z = fmaxf(st.z, 0.f); st.w = fmaxf(st.w, 0.f);
    }
    *(float4*)&hout[n * 64 + k4] = st;
  }
}

// ---------------- fused edge scores via LDS-staged P/Q chunks ----------------
// grid: 256 blocks; g = blockIdx & 127 (pair {g, g+128} shares XCD -> L2 reuse of pq)
// LDS layout Ps[k][node] (k chunk-local 0..31): bank = node%32, random nodes => ~2/bank (free)
__global__ __launch_bounds__(256, 2) void score_v2(const float* __restrict__ pq, const int* __restrict__ ei,
                                                   const float* __restrict__ wm2, const float* __restrict__ bm2,
                                                   float* __restrict__ out) {
  __shared__ float Ps[32 * 256];  // 32 KB
  __shared__ float Qs[32 * 256];  // 32 KB
  const int tid = threadIdx.x;
  const int g = blockIdx.x & 127;
  const int half = blockIdx.x >> 7;
  const int gbase = g * NPG_;
  const int ebase = g * EPG_ + half * 2048;
  int rl[8], cl[8];
  float acc[8] = {};
#pragma unroll
  for (int j = 0; j < 8; ++j) {
    int e = ebase + j * 256 + tid;
    rl[j] = ei[e] - gbase;
    cl[j] = ei[EE_ + e] - gbase;
  }
  for (int t = 0; t < 8; ++t) {
    __syncthreads();
#pragma unroll
    for (int it = 0; it < 8; ++it) {
      int idx = tid + it * 256;           // 0..2047
      int node = idx >> 3, k4 = (idx & 7) * 4;
      const float* src = &pq[(size_t)(gbase + node) * 512 + t * 32 + k4];
      float4 p = *(const float4*)src;
      float4 q = *(const float4*)(src + 256);
      Ps[(k4 + 0) * 256 + node] = p.x;
      Ps[(k4 + 1) * 256 + node] = p.y;
      Ps[(k4 + 2) * 256 + node] = p.z;
      Ps[(k4 + 3) * 256 + node] = p.w;
      Qs[(k4 + 0) * 256 + node] = q.x;
      Qs[(k4 + 1) * 256 + node] = q.y;
      Qs[(k4 + 2) * 256 + node] = q.z;
      Qs[(k4 + 3) * 256 + node] = q.w;
    }
    __syncthreads();
#pragma unroll
    for (int k = 0; k < 32; ++k) {
      float wk = wm2[t * 32 + k];
#pragma unroll
      for (int j = 0; j < 8; ++j) {
        float pv = Ps[k * 256 + rl[j]];
        float qv = Qs[k * 256 + cl[j]];
        acc[j] = fmaf(wk, fmaxf(pv + qv, 0.f), acc[j]);
      }
    }
  }
  const float beta = bm2[0];
#pragma unroll
  for (int j = 0; j < 8; ++j) out[ebase + j * 256 + tid] = acc[j] + beta;
}

// ---------------- per-group stable-descending bitonic argsort + top-K split ----------------
__global__ __launch_bounds__(1024) void sort_kernel(float* __restrict__ out, const int* __restrict__ ei,
                                                    int* __restrict__ kg, int* __restrict__ dg,
                                                    int* __restrict__ cmask, int* __restrict__ dmask) {
  __shared__ unsigned long long keys[EPG_];
  const int g = blockIdx.x;
  const int tid = threadIdx.x;
  for (int i = tid; i < EPG_; i += 1024) {
    float s = out[g * EPG_ + i];
    unsigned u = __float_as_uint(s);
    u = (u & 0x80000000u) ? ~u : (u | 0x80000000u);
    keys[i] = ((unsigned long long)u << 32) | (unsigned)(~i);
  }
  __syncthreads();
  for (int k = 2; k <= EPG_; k <<= 1) {
    for (int j = k >> 1; j > 0; j >>= 1) {
      for (int i = tid; i < EPG_; i += 1024) {
        int ixj = i ^ j;
        if (ixj > i) {
          unsigned long long a = keys[i], b = keys[ixj];
          bool desc = ((i & k) == 0);
          if ((a < b) == desc) { keys[i] = b; keys[ixj] = a; }
        }
      }
      __syncthreads();
    }
  }
  for (int p = tid; p < EPG_; p += 1024) {
    unsigned long long kv = keys[p];
    int i = (int)(~(unsigned)kv);
    unsigned hi = (unsigned)(kv >> 32);
    unsigned ub = (hi & 0x80000000u) ? (hi ^ 0x80000000u) : ~hi;
    float s = __uint_as_float(ub);
    int e = g * EPG_ + i;
    int r = ei[e], c = ei[EE_ + e];
    if (p < KK_) {
      out[O_CW + g * KK_ + p] = s;
      kg[g * KK_ + p] = e;
      cmask[r] = 1; cmask[c] = 1;
    } else {
      int q = p - KK_;
      out[O_DW + g * KK_ + q] = -s;
      dg[g * KK_ + q] = e;
      dmask[r] = 1; dmask[c] = 1;
    }
  }
}

// ---------------- inclusive scan of masks -> nid (cumsum-1); 1 block per mask ----------------
__global__ __launch_bounds__(1024) void scan_kernel(const int* __restrict__ masks, int* __restrict__ nids) {
  const int which = blockIdx.x;
  const int* m = masks + which * NN_;
  int* nid = nids + which * NN_;
  const int tid = threadIdx.x;
  const int base = tid * 32;
  int local[32];
  int sum = 0;
#pragma unroll
  for (int j = 0; j < 32; ++j) { local[j] = m[base + j]; sum += local[j]; }
  __shared__ int ps[1024];
  ps[tid] = sum;
  __syncthreads();
  for (int off = 1; off < 1024; off <<= 1) {
    int v = (tid >= off) ? ps[tid - off] : 0;
    __syncthreads();
    ps[tid] += v;
    __syncthreads();
  }
  int run = ps[tid] - sum;
#pragma unroll
  for (int j = 0; j < 32; ++j) { run += local[j]; nid[base + j] = run - 1; }
}

// ---------------- final gathers ----------------
__global__ __launch_bounds__(256) void finalize_kernel(const int* __restrict__ kg, const int* __restrict__ dg,
                                                       const int* __restrict__ ei,
                                                       const int* __restrict__ nid_c, const int* __restrict__ nid_d,
                                                       const int* __restrict__ cmask, const int* __restrict__ dmask,
                                                       float* __restrict__ out) {
  const int p = blockIdx.x * 256 + threadIdx.x;
  int e = kg[p];
  out[O_CEI + p]       = (float)nid_c[ei[e]];
  out[O_CEI + GK_ + p] = (float)nid_c[ei[EE_ + e]];
  int e2 = dg[p];
  out[O_FEI + p]       = (float)nid_d[ei[e2]];
  out[O_FEI + GK_ + p] = (float)nid_d[ei[EE_ + e2]];
  if (p < NN_) {
    out[O_CM + p] = (float)cmask[p];
    out[O_DM + p] = (float)dmask[p];
  }
}

extern "C" void kernel_launch(void* const* d_in, const int* in_sizes, int n_in,
                              void* d_out, int out_size, void* d_ws, size_t ws_size,
                              hipStream_t stream) {
  (void)in_sizes; (void)n_in; (void)out_size; (void)ws_size;
  const float* x   = (const float*)d_in[0];
  const float* ea  = (const float*)d_in[1];
  const float* W11 = (const float*)d_in[2];
  const float* b11 = (const float*)d_in[3];
  const float* W12 = (const float*)d_in[4];
  const float* W13 = (const float*)d_in[5];
  const float* b13 = (const float*)d_in[6];
  const float* W21 = (const float*)d_in[7];
  const float* b21 = (const float*)d_in[8];
  const float* W22 = (const float*)d_in[9];
  const float* W23 = (const float*)d_in[10];
  const float* b23 = (const float*)d_in[11];
  const float* Wm1 = (const float*)d_in[12];
  const float* bm1 = (const float*)d_in[13];
  const float* Wm2 = (const float*)d_in[14];
  const float* bm2 = (const float*)d_in[15];
  const int*   ei  = (const int*)d_in[16];
  float* out = (float*)d_out;
  float* ws  = (float*)d_ws;

  // workspace (float offsets), phase-overlapped (78.2 MB total):
  //   MT  [0, 8388608)          32 MB  (dead after mm_agg #2)
  //   buf [8388608, 14680064)   24 MB  (dead after mm_agg #2)
  //   Wc  [14680064, 14712832)  128 KB (dead after mm_agg #2)
  //   pq  [0, 16777216)         64 MB  overlaps MT/buf/Wc, written after both dead
  //   h_c [16777216, 18874368)  8 MB
  //   ints from 18874368: kg GK, dg GK, cmask N, dmask N, nid_c N, nid_d N
  float* MT  = ws;
  float* buf = ws + 8388608;
  float* Wc  = ws + 14680064;
  float* pq  = ws;
  float* h_c = ws + 16777216;
  int* kg    = (int*)(ws + 18874368);
  int* dg    = kg + GK_;
  int* cmask = dg + GK_;
  int* dmask = cmask + NN_;
  int* nid_c = dmask + NN_;
  int* nid_d = nid_c + NN_;

  hipMemsetAsync(MT, 0, (size_t)G_ * NPG_ * NPG_ * sizeof(float), stream);
  hipMemsetAsync(Wc, 0, NN_ * sizeof(float), stream);
  hipMemsetAsync(cmask, 0, 2 * NN_ * sizeof(int), stream);

  build_M<<<EE_ / 256, 256, 0, stream>>>(ei, ea, MT, Wc);

  GemmCfg c1{};
  c1.w[0] = W11; c1.w[1] = W12; c1.w[2] = W13;
  c1.b[0] = b11; c1.b[1] = nullptr; c1.b[2] = b13;
  c1.wstride = 64;
  gemm_k64<<<512, 256, 0, stream>>>(x, 64, c1, 3, buf, 192);

  mm_agg<<<512, 256, 0, stream>>>(MT, buf, Wc, h_c, /*relu=*/1);

  GemmCfg c2{};
  c2.w[0] = W21; c2.w[1] = W22; c2.w[2] = W23;
  c2.b[0] = b21; c2.b[1] = nullptr; c2.b[2] = b23;
  c2.wstride = 64;
  gemm_k64<<<512, 256, 0, stream>>>(h_c, 64, c2, 3, buf, 192);

  mm_agg<<<512, 256, 0, stream>>>(MT, buf, Wc, h_c, /*relu=*/0);

  GemmCfg c3{};
  for (int cb = 0; cb < 4; ++cb) { c3.w[cb] = Wm1 + cb * 64 * 128;            c3.b[cb] = bm1 + cb * 64; }
  for (int cb = 4; cb < 8; ++cb) { c3.w[cb] = Wm1 + (cb - 4) * 64 * 128 + 64; c3.b[cb] = nullptr; }
  c3.wstride = 128;
  gemm_k64<<<512, 256, 0, stream>>>(h_c, 64, c3, 8, pq, 512);

  score_v2<<<256, 256, 0, stream>>>(pq, ei, Wm2, bm2, out);

  sort_kernel<<<G_, 1024, 0, stream>>>(out, ei, kg, dg, cmask, dmask);

  scan_kernel<<<2, 1024, 0, stream>>>(cmask, nid_c);

  finalize_kernel<<<GK_ / 256, 256, 0, stream>>>(kg, dg, ei, nid_c, nid_d, cmask, dmask, out);
}